// Round 1
// 787.010 us; speedup vs baseline: 1.0429x; 1.0429x over previous
//
#include <hip/hip_runtime.h>

// B=2, S=2048, D=1024, H=16, d_k=64, WINDOW=256
// d_out = out [B,S,D] fp32  ++  attn [B,H,S,S] fp32
// ws (112 MB): Xs bf16 3x[4096x2048] | XsAO bf16 [4096x2048] | Wt bf16 4x[1024x2048]
//              | Qb,Kb,Vb bf16 [4096x1024] | Vt bf16 [B,H,64,2048]

constexpr int Bb = 2, Ss = 2048, Dd = 1024, Hh = 16, WINw = 256;
constexpr size_t XS_SLAB = (size_t)4096 * 2048;  // bf16 elems
constexpr size_t WT_SLAB = (size_t)1024 * 2048;  // bf16 elems
constexpr size_t QB_SLAB = (size_t)4096 * 1024;  // bf16 elems

typedef short s16x8 __attribute__((ext_vector_type(8)));
typedef float f32x4 __attribute__((ext_vector_type(4)));

typedef __attribute__((address_space(3))) unsigned int lds_uint;
typedef const __attribute__((address_space(1))) unsigned int gbl_uint;

// async global->LDS, 16B per lane; LDS dest = wave-uniform base + lane*16
__device__ __forceinline__ void gld_lds16(const void* g, void* l) {
  __builtin_amdgcn_global_load_lds((gbl_uint*)g, (lds_uint*)l, 16, 0, 0);
}

__device__ inline unsigned short f2bf(float x) {
  unsigned u = __float_as_uint(x);
  u += 0x7fff + ((u >> 16) & 1);  // RNE
  return (unsigned short)(u >> 16);
}
__device__ inline float bf2f(unsigned short h) {
  return __uint_as_float(((unsigned)h) << 16);
}

// ---------------------------------------------------------------------------
// fp32 [4096x1024] -> bf16 split [4096x2048] = [hi | lo]; z selects source.
// ---------------------------------------------------------------------------
__global__ __launch_bounds__(256) void convert_x(
    const float* __restrict__ x0, const float* __restrict__ x1,
    const float* __restrict__ x2, unsigned short* __restrict__ Xs) {
  int z = blockIdx.z;
  const float* src = z == 0 ? x0 : (z == 1 ? x1 : x2);
  unsigned short* dst = Xs + (size_t)z * XS_SLAB;
  size_t idx = ((size_t)blockIdx.x * 256 + threadIdx.x) * 4;
  int r = (int)(idx >> 10);
  int c = (int)(idx & 1023);
  f32x4 v = *(const f32x4*)&src[idx];
  unsigned short hi[4], lo[4];
#pragma unroll
  for (int i = 0; i < 4; ++i) {
    float vi = v[i];
    hi[i] = f2bf(vi);
    lo[i] = f2bf(vi - bf2f(hi[i]));
  }
  ushort4 h4 = {hi[0], hi[1], hi[2], hi[3]};
  ushort4 l4 = {lo[0], lo[1], lo[2], lo[3]};
  *(ushort4*)&dst[(size_t)r * 2048 + c] = h4;
  *(ushort4*)&dst[(size_t)r * 2048 + 1024 + c] = l4;
}

// ---------------------------------------------------------------------------
// W [1024x1024] fp32 -> Wt bf16 [n][2048] = [W_hi^T | W_lo^T] (transposed).
// ---------------------------------------------------------------------------
__global__ __launch_bounds__(256) void convert_w(
    const float* __restrict__ w0, const float* __restrict__ w1,
    const float* __restrict__ w2, const float* __restrict__ w3,
    unsigned short* __restrict__ Wt) {
  __shared__ float T[64][65];
  int z = blockIdx.z;
  const float* W = z == 0 ? w0 : (z == 1 ? w1 : (z == 2 ? w2 : w3));
  unsigned short* dst = Wt + (size_t)z * WT_SLAB;
  int k0 = blockIdx.y * 64, n0 = blockIdx.x * 64;
  int t = threadIdx.x;
#pragma unroll
  for (int i = 0; i < 4; ++i) {
    int row = (t >> 4) + i * 16;
    int c4 = (t & 15) * 4;
    f32x4 v = *(const f32x4*)&W[(size_t)(k0 + row) * 1024 + n0 + c4];
    T[row][c4 + 0] = v[0]; T[row][c4 + 1] = v[1];
    T[row][c4 + 2] = v[2]; T[row][c4 + 3] = v[3];
  }
  __syncthreads();
  int n = t >> 2;
  int kc = (t & 3) * 16;
  unsigned short hi[16], lo[16];
#pragma unroll
  for (int j = 0; j < 16; ++j) {
    float x = T[kc + j][n];
    hi[j] = f2bf(x);
    lo[j] = f2bf(x - bf2f(hi[j]));
  }
  size_t base = (size_t)(n0 + n) * 2048 + k0 + kc;
#pragma unroll
  for (int j4 = 0; j4 < 4; ++j4) {
    ushort4 h4 = {hi[j4 * 4], hi[j4 * 4 + 1], hi[j4 * 4 + 2], hi[j4 * 4 + 3]};
    ushort4 l4 = {lo[j4 * 4], lo[j4 * 4 + 1], lo[j4 * 4 + 2], lo[j4 * 4 + 3]};
    *(ushort4*)&dst[base + j4 * 4] = h4;
    *(ushort4*)&dst[base + 1024 + j4 * 4] = l4;
  }
}

// ---------------------------------------------------------------------------
// C[4096x1024] = Abig[4096x3072] @ Wbig[3072x1024] + bias, bf16x3 split.
// F32OUT=1: fp32 C (final out-proj). F32OUT=0: bf16 C (QKV; z=0 scaled 1/8).
// v2: global_load_lds staging (m151: +35% vs reg-staging), double-buffered
//     LDS, single barrier per K-step (T3 minimal 2-phase recipe).
//     Swizzled layout preserved via pre-swizzled per-lane GLOBAL addresses
//     (linear LDS dest, rule #21).
// ---------------------------------------------------------------------------
template <int F32OUT>
__global__ __launch_bounds__(256, 3) void gemm_bf16x3(
    const unsigned short* __restrict__ Abase,
    const unsigned short* __restrict__ Wtbase, void* __restrict__ Cbase,
    const float* __restrict__ bb0, const float* __restrict__ bb1,
    const float* __restrict__ bb2) {
  __shared__ s16x8 As[2][512];
  __shared__ s16x8 Bs[2][512];
  int z = blockIdx.z;
  const unsigned short* A = Abase + (size_t)z * XS_SLAB;
  const unsigned short* Wt = Wtbase + (size_t)z * WT_SLAB;
  const float* bias = z == 0 ? bb0 : (z == 1 ? bb1 : bb2);
  const float scl = (!F32OUT && z == 0) ? 0.125f : 1.0f;

  const int t = threadIdx.x;
  const int lane = t & 63, wave = t >> 6;
  const int wm = wave & 1, wn = wave >> 1;
  const int bm = blockIdx.y * 128, bn = blockIdx.x * 128;

  f32x4 acc[4][4] = {};

  // slot s0 = t = wave*64+lane; slot s1 = t+256. XOR-swizzled source columns.
  const int s0 = t, s1 = t + 256;
  const int r0 = s0 >> 2, c0 = (s0 & 3) ^ ((r0 >> 1) & 3);
  const int r1 = s1 >> 2, c1 = (s1 & 3) ^ ((r1 >> 1) & 3);
  const unsigned short* A0 = A + (size_t)(bm + r0) * 2048 + c0 * 8;
  const unsigned short* A1 = A + (size_t)(bm + r1) * 2048 + c1 * 8;
  const unsigned short* B0 = Wt + (size_t)(bn + r0) * 2048 + c0 * 8;
  const unsigned short* B1 = Wt + (size_t)(bn + r1) * 2048 + c1 * 8;

  const int m15 = lane & 15, q = lane >> 4;

  // prologue: stage K-tile 0 into buffer 0
  gld_lds16(A0, &As[0][wave * 64]);
  gld_lds16(A1, &As[0][256 + wave * 64]);
  gld_lds16(B0, &Bs[0][wave * 64]);
  gld_lds16(B1, &Bs[0][256 + wave * 64]);
  __syncthreads();  // drains vmcnt(0) before s_barrier

  int cur = 0;
  for (int kb = 0; kb < 3072; kb += 32) {
    const int kn = kb + 32;
    if (kn < 3072) {
      // bf16x3: segments are A_hi*W_hi | A_hi*W_lo | A_lo*W_hi
      int asrc = kn < 1024 ? kn : kn - 1024;
      int wsrc = kn < 2048 ? kn : kn - 2048;
      gld_lds16(A0 + asrc, &As[cur ^ 1][wave * 64]);
      gld_lds16(A1 + asrc, &As[cur ^ 1][256 + wave * 64]);
      gld_lds16(B0 + wsrc, &Bs[cur ^ 1][wave * 64]);
      gld_lds16(B1 + wsrc, &Bs[cur ^ 1][256 + wave * 64]);
    }

    s16x8 af[4], bf[4];
#pragma unroll
    for (int mt = 0; mt < 4; ++mt) {
      int r = wm * 64 + mt * 16 + m15;
      af[mt] = As[cur][r * 4 + (q ^ ((r >> 1) & 3))];
    }
#pragma unroll
    for (int nt = 0; nt < 4; ++nt) {
      int r = wn * 64 + nt * 16 + m15;
      bf[nt] = Bs[cur][r * 4 + (q ^ ((r >> 1) & 3))];
    }
#pragma unroll
    for (int mt = 0; mt < 4; ++mt)
#pragma unroll
      for (int nt = 0; nt < 4; ++nt)
        acc[mt][nt] = __builtin_amdgcn_mfma_f32_16x16x32_bf16(
            af[mt], bf[nt], acc[mt][nt], 0, 0, 0);

    if (kn < 3072) {
      __syncthreads();  // vmcnt(0)+lgkmcnt(0) drain: next buffer ready
      cur ^= 1;
    }
  }

#pragma unroll
  for (int nt = 0; nt < 4; ++nt) {
    int col = bn + wn * 64 + nt * 16 + m15;
    float bv = bias[col];
#pragma unroll
    for (int mt = 0; mt < 4; ++mt) {
      int rowb = bm + wm * 64 + mt * 16 + q * 4;
#pragma unroll
      for (int i = 0; i < 4; ++i) {
        float val = (acc[mt][nt][i] + bv) * scl;
        if (F32OUT) {
          __builtin_nontemporal_store(
              val, &((float*)Cbase)[(size_t)(rowb + i) * 1024 + col]);
        } else {
          ((unsigned short*)Cbase + (size_t)z * QB_SLAB)
              [(size_t)(rowb + i) * 1024 + col] = f2bf(val);
        }
      }
    }
  }
}

// ---------------------------------------------------------------------------
// Vb [4096][1024] bf16 -> Vt [b][h][d][s] bf16 (per-head transposed).
// ---------------------------------------------------------------------------
__global__ __launch_bounds__(256) void transpose_v(
    const unsigned short* __restrict__ Vb, unsigned short* __restrict__ Vt) {
  __shared__ unsigned short T[64][88];
  const int b = blockIdx.z, h = blockIdx.y, s0 = blockIdx.x * 64;
  const int t = threadIdx.x;
  {
    int row = t >> 2, part = t & 3;
    const unsigned short* src =
        Vb + (size_t)(b * Ss + s0 + row) * 1024 + h * 64 + part * 16;
    s16x8 v0 = *(const s16x8*)src;
    s16x8 v1 = *(const s16x8*)(src + 8);
    *(s16x8*)&T[row][part * 16] = v0;
    *(s16x8*)&T[row][part * 16 + 8] = v1;
  }
  __syncthreads();
  {
    int d = t & 63, sw = t >> 6;
    unsigned short tmp[16];
#pragma unroll
    for (int i = 0; i < 16; ++i) tmp[i] = T[sw * 16 + i][d];
    unsigned short* dst =
        Vt + ((size_t)((b * Hh + h) * 64 + d)) * 2048 + s0 + sw * 16;
    *(s16x8*)dst = *(const s16x8*)&tmp[0];
    *(s16x8*)(dst + 8) = *(const s16x8*)&tmp[8];
  }
}

// ---------------------------------------------------------------------------
// Fused attention v3: per block = one (b,h) x 16-query tile, 4 waves.
// S1: scores via MFMA (Q pre-scaled 1/8) -> LDS P fp32.
// S2: per-row softmax; write full 2048-wide attn rows (NONTEMPORAL: attn is
//     write-once-never-read; keep L2 for the K/V panels); probs back to LDS.
// S3: PV via MFMA (A = P rows cvt bf16 from LDS, B = Vt rows contiguous);
//     epilogue writes AO directly as hi/lo bf16 (Xs layout) for out-proj.
// ---------------------------------------------------------------------------
constexpr int SW3 = 556;  // f32 stride: 556%32=12 -> <=2-way banks; 16B-aligned
__global__ __launch_bounds__(256) void attn_v3(
    const unsigned short* __restrict__ Qb, const unsigned short* __restrict__ Kb,
    const unsigned short* __restrict__ Vt, float* __restrict__ attn,
    unsigned short* __restrict__ XsAO) {
  __shared__ float P[16 * SW3];  // 35.6 KB
  const int t = threadIdx.x;
  const int lane = t & 63, wave = t >> 6;
  const int m15 = lane & 15, quad = lane >> 4;
  const int bid = blockIdx.x;
  const int qt = bid & 127, h = (bid >> 7) & 15, b = bid >> 11;
  const int q0 = qt * 16;
  int jlo = q0 - WINw; if (jlo < 0) jlo = 0;
  int jhi = q0 + 15 + WINw; if (jhi > Ss - 1) jhi = Ss - 1;
  const int ncols = jhi - jlo + 1;  // always a multiple of 16
  const int ntiles = ncols >> 4;

  // ---- stage 1: scores via MFMA -> P ----
  {
    const unsigned short* qrow =
        Qb + (size_t)(b * Ss + q0 + m15) * 1024 + h * 64 + quad * 8;
    s16x8 aq0 = *(const s16x8*)qrow;
    s16x8 aq1 = *(const s16x8*)(qrow + 32);
    for (int nt = wave; nt < ntiles; nt += 4) {
      const unsigned short* krow =
          Kb + (size_t)(b * Ss + jlo + nt * 16 + m15) * 1024 + h * 64 + quad * 8;
      s16x8 b0 = *(const s16x8*)krow;
      s16x8 b1 = *(const s16x8*)(krow + 32);
      f32x4 c = {0.f, 0.f, 0.f, 0.f};
      c = __builtin_amdgcn_mfma_f32_16x16x32_bf16(aq0, b0, c, 0, 0, 0);
      c = __builtin_amdgcn_mfma_f32_16x16x32_bf16(aq1, b1, c, 0, 0, 0);
      float* pp = &P[(quad * 4) * SW3 + nt * 16 + m15];
#pragma unroll
      for (int i = 0; i < 4; ++i) pp[i * SW3] = c[i];
    }
  }
  __syncthreads();

  // ---- stage 2: softmax + attn row write + probs -> LDS ----
  {
#pragma unroll
    for (int ri = 0; ri < 4; ++ri) {
      const int r = wave * 4 + ri;
      const int qq = q0 + r;
      int lo = qq - WINw; if (lo < 0) lo = 0;
      int hi = qq + WINw; if (hi > Ss - 1) hi = Ss - 1;
      const int clo = lo - jlo, chi = hi - jlo;
      float sv[9];
      bool ib[9];
      float m = -1e30f;
#pragma unroll
      for (int k2 = 0; k2 < 9; ++k2) {
        int c = k2 * 64 + lane;
        bool inb = (c >= clo) && (c <= chi);
        ib[k2] = inb;
        float vv = inb ? P[r * SW3 + c] : -1e30f;
        sv[k2] = vv;
        m = fmaxf(m, vv);
      }
#pragma unroll
      for (int off = 32; off; off >>= 1) m = fmaxf(m, __shfl_xor(m, off, 64));
      float e[9], l = 0.f;
#pragma unroll
      for (int k2 = 0; k2 < 9; ++k2) { e[k2] = __expf(sv[k2] - m); l += e[k2]; }
#pragma unroll
      for (int off = 32; off; off >>= 1) l += __shfl_xor(l, off, 64);
      const float inv = 1.f / l;
#pragma unroll
      for (int k2 = 0; k2 < 9; ++k2) {
        int c = k2 * 64 + lane;
        if (c < 544) P[r * SW3 + c] = ib[k2] ? e[k2] * inv : 0.f;
      }
      float* arow = attn + ((size_t)((b * Hh + h) * Ss + qq)) * Ss;
#pragma unroll
      for (int i = 0; i < 8; ++i) {
        int col = i * 256 + lane * 4;
        int c = col - jlo;
        f32x4 v = {0.f, 0.f, 0.f, 0.f};
        if (c >= 0 && c <= 540) v = *(const f32x4*)&P[r * SW3 + c];
        __builtin_nontemporal_store(v, (f32x4*)&arow[col]);
      }
    }
  }
  __syncthreads();

  // ---- stage 3: PV via MFMA; wave = d-tile ----
  {
    const int ntk = (ncols + 31) >> 5;
    const unsigned short* vtrow =
        Vt + ((size_t)((b * Hh + h) * 64 + wave * 16 + m15)) * 2048 + jlo +
        quad * 8;
    f32x4 o = {0.f, 0.f, 0.f, 0.f};
    for (int ks = 0; ks < ntk; ++ks) {
      const float* pa = &P[m15 * SW3 + ks * 32 + quad * 8];
      f32x4 p0 = *(const f32x4*)pa;
      f32x4 p1 = *(const f32x4*)(pa + 4);
      s16x8 af;
#pragma unroll
      for (int i = 0; i < 4; ++i) af[i] = (short)f2bf(p0[i]);
#pragma unroll
      for (int i = 0; i < 4; ++i) af[4 + i] = (short)f2bf(p1[i]);
      s16x8 bf = *(const s16x8*)(vtrow + ks * 32);
      o = __builtin_amdgcn_mfma_f32_16x16x32_bf16(af, bf, o, 0, 0, 0);
    }
    const int dcol = h * 64 + wave * 16 + m15;
#pragma unroll
    for (int i = 0; i < 4; ++i) {
      int row = q0 + quad * 4 + i;
      unsigned short hi = f2bf(o[i]);
      unsigned short lo = f2bf(o[i] - bf2f(hi));
      unsigned short* dst = XsAO + (size_t)(b * Ss + row) * 2048 + dcol;
      dst[0] = hi;
      dst[1024] = lo;
    }
  }
}

// ---------------------------------------------------------------------------
extern "C" void kernel_launch(void* const* d_in, const int* in_sizes, int n_in,
                              void* d_out, int out_size, void* d_ws,
                              size_t ws_size, hipStream_t stream) {
  const float* q  = (const float*)d_in[0];
  const float* k  = (const float*)d_in[1];
  const float* v  = (const float*)d_in[2];
  const float* Wq = (const float*)d_in[3];
  const float* bq = (const float*)d_in[4];
  const float* Wk = (const float*)d_in[5];
  const float* bk = (const float*)d_in[6];
  const float* Wv = (const float*)d_in[7];
  const float* bv = (const float*)d_in[8];
  const float* Wo = (const float*)d_in[9];
  const float* bo = (const float*)d_in[10];

  float* out = (float*)d_out;
  float* attn = out + (size_t)Bb * Ss * Dd;

  unsigned short* Xs   = (unsigned short*)d_ws;   // 48 MB
  unsigned short* XsAO = Xs + 3 * XS_SLAB;        // 16 MB
  unsigned short* Wt   = XsAO + XS_SLAB;          // 16 MB
  unsigned short* Qb   = Wt + 4 * WT_SLAB;        // 8 MB
  unsigned short* Kb   = Qb + QB_SLAB;            // 8 MB
  unsigned short* Vb   = Kb + QB_SLAB;            // 8 MB
  unsigned short* Vt   = Vb + QB_SLAB;            // 8 MB (+slack after)

  hipLaunchKernelGGL(convert_x, dim3(4096, 1, 3), dim3(256), 0, stream,
                     q, k, v, Xs);
  hipLaunchKernelGGL(convert_w, dim3(16, 16, 4), dim3(256), 0, stream,
                     Wq, Wk, Wv, Wo, Wt);
  hipLaunchKernelGGL((gemm_bf16x3<0>), dim3(8, 32, 3), dim3(256), 0, stream,
                     Xs, Wt, (void*)Qb, bq, bk, bv);
  hipLaunchKernelGGL(transpose_v, dim3(32, 16, 2), dim3(256), 0, stream,
                     Vb, Vt);
  hipLaunchKernelGGL(attn_v3, dim3(Bb * Hh * (Ss / 16)), dim3(256), 0, stream,
                     Qb, Kb, Vt, attn, XsAO);
  hipLaunchKernelGGL((gemm_bf16x3<1>), dim3(8, 32, 1), dim3(256), 0, stream,
                     XsAO, Wt + 3 * WT_SLAB, (void*)out, bo, bo, bo);
}

// Round 2
// 784.104 us; speedup vs baseline: 1.0468x; 1.0037x over previous
//
#include <hip/hip_runtime.h>

// B=2, S=2048, D=1024, H=16, d_k=64, WINDOW=256
// d_out = out [B,S,D] fp32  ++  attn [B,H,S,S] fp32
// ws (112 MB): Xs bf16 3x[4096x2048] | XsAO bf16 [4096x2048] | Wt bf16 4x[1024x2048]
//              | Qb,Kb,Vb bf16 [4096x1024] | Vt bf16 [B,H,64,2048]

constexpr int Bb = 2, Ss = 2048, Dd = 1024, Hh = 16, WINw = 256;
constexpr size_t XS_SLAB = (size_t)4096 * 2048;  // bf16 elems
constexpr size_t WT_SLAB = (size_t)1024 * 2048;  // bf16 elems
constexpr size_t QB_SLAB = (size_t)4096 * 1024;  // bf16 elems

typedef short s16x8 __attribute__((ext_vector_type(8)));
typedef float f32x4 __attribute__((ext_vector_type(4)));

typedef __attribute__((address_space(3))) unsigned int lds_uint;
typedef const __attribute__((address_space(1))) unsigned int gbl_uint;

// async global->LDS, 16B per lane; LDS dest = wave-uniform base + lane*16
__device__ __forceinline__ void gld_lds16(const void* g, void* l) {
  __builtin_amdgcn_global_load_lds((gbl_uint*)g, (lds_uint*)l, 16, 0, 0);
}

// producer-side barrier: drain LDS ops only (NOT vmcnt) then s_barrier.
// Lets outstanding global stores keep draining across the barrier.
__device__ __forceinline__ void lgkm_barrier() {
  asm volatile("s_waitcnt lgkmcnt(0)" ::: "memory");
  __builtin_amdgcn_s_barrier();
}

__device__ inline unsigned short f2bf(float x) {
  unsigned u = __float_as_uint(x);
  u += 0x7fff + ((u >> 16) & 1);  // RNE
  return (unsigned short)(u >> 16);
}
__device__ inline float bf2f(unsigned short h) {
  return __uint_as_float(((unsigned)h) << 16);
}

// ---------------------------------------------------------------------------
// Merged conversions (single dispatch, saves a launch boundary).
// id < 12288 : convert_x — fp32 [4096x1024] -> bf16 split [4096x2048]=[hi|lo]
// id >= 12288: convert_w — W [1024x1024] fp32 -> Wt bf16 [n][2048]=[Whi^T|Wlo^T]
// ---------------------------------------------------------------------------
__global__ __launch_bounds__(256) void convert_xw(
    const float* __restrict__ x0, const float* __restrict__ x1,
    const float* __restrict__ x2, unsigned short* __restrict__ Xs,
    const float* __restrict__ w0, const float* __restrict__ w1,
    const float* __restrict__ w2, const float* __restrict__ w3,
    unsigned short* __restrict__ Wt) {
  __shared__ float T[64][65];
  const int id = blockIdx.x;
  const int t = threadIdx.x;
  if (id < 12288) {
    // ---- convert_x ----
    int z = id >> 12;
    int bx = id & 4095;
    const float* src = z == 0 ? x0 : (z == 1 ? x1 : x2);
    unsigned short* dst = Xs + (size_t)z * XS_SLAB;
    size_t idx = ((size_t)bx * 256 + t) * 4;
    int r = (int)(idx >> 10);
    int c = (int)(idx & 1023);
    f32x4 v = *(const f32x4*)&src[idx];
    unsigned short hi[4], lo[4];
#pragma unroll
    for (int i = 0; i < 4; ++i) {
      float vi = v[i];
      hi[i] = f2bf(vi);
      lo[i] = f2bf(vi - bf2f(hi[i]));
    }
    ushort4 h4 = {hi[0], hi[1], hi[2], hi[3]};
    ushort4 l4 = {lo[0], lo[1], lo[2], lo[3]};
    *(ushort4*)&dst[(size_t)r * 2048 + c] = h4;
    *(ushort4*)&dst[(size_t)r * 2048 + 1024 + c] = l4;
  } else {
    // ---- convert_w ----
    int wid = id - 12288;
    int z = wid >> 8;
    int by = (wid >> 4) & 15;
    int bx = wid & 15;
    const float* W = z == 0 ? w0 : (z == 1 ? w1 : (z == 2 ? w2 : w3));
    unsigned short* dst = Wt + (size_t)z * WT_SLAB;
    int k0 = by * 64, n0 = bx * 64;
#pragma unroll
    for (int i = 0; i < 4; ++i) {
      int row = (t >> 4) + i * 16;
      int c4 = (t & 15) * 4;
      f32x4 v = *(const f32x4*)&W[(size_t)(k0 + row) * 1024 + n0 + c4];
      T[row][c4 + 0] = v[0]; T[row][c4 + 1] = v[1];
      T[row][c4 + 2] = v[2]; T[row][c4 + 3] = v[3];
    }
    __syncthreads();
    int n = t >> 2;
    int kc = (t & 3) * 16;
    unsigned short hi[16], lo[16];
#pragma unroll
    for (int j = 0; j < 16; ++j) {
      float x = T[kc + j][n];
      hi[j] = f2bf(x);
      lo[j] = f2bf(x - bf2f(hi[j]));
    }
    size_t base = (size_t)(n0 + n) * 2048 + k0 + kc;
#pragma unroll
    for (int j4 = 0; j4 < 4; ++j4) {
      ushort4 h4 = {hi[j4 * 4], hi[j4 * 4 + 1], hi[j4 * 4 + 2], hi[j4 * 4 + 3]};
      ushort4 l4 = {lo[j4 * 4], lo[j4 * 4 + 1], lo[j4 * 4 + 2], lo[j4 * 4 + 3]};
      *(ushort4*)&dst[base + j4 * 4] = h4;
      *(ushort4*)&dst[base + 1024 + j4 * 4] = l4;
    }
  }
}

// ---------------------------------------------------------------------------
// C[4096x1024] = Abig[4096x3072] @ Wbig[3072x1024] + bias, bf16x3 split.
// QKV path (bf16 out; z=0 scaled 1/8). 128x128 tile, global_load_lds staging,
// double-buffered LDS, single barrier per K-step.
// ---------------------------------------------------------------------------
__global__ __launch_bounds__(256, 3) void gemm_qkv(
    const unsigned short* __restrict__ Abase,
    const unsigned short* __restrict__ Wtbase,
    unsigned short* __restrict__ Cbase, const float* __restrict__ bb0,
    const float* __restrict__ bb1, const float* __restrict__ bb2) {
  __shared__ s16x8 As[2][512];
  __shared__ s16x8 Bs[2][512];
  int z = blockIdx.z;
  const unsigned short* A = Abase + (size_t)z * XS_SLAB;
  const unsigned short* Wt = Wtbase + (size_t)z * WT_SLAB;
  const float* bias = z == 0 ? bb0 : (z == 1 ? bb1 : bb2);
  const float scl = (z == 0) ? 0.125f : 1.0f;

  const int t = threadIdx.x;
  const int lane = t & 63, wave = t >> 6;
  const int wm = wave & 1, wn = wave >> 1;
  const int bm = blockIdx.y * 128, bn = blockIdx.x * 128;

  f32x4 acc[4][4] = {};

  const int s0 = t, s1 = t + 256;
  const int r0 = s0 >> 2, c0 = (s0 & 3) ^ ((r0 >> 1) & 3);
  const int r1 = s1 >> 2, c1 = (s1 & 3) ^ ((r1 >> 1) & 3);
  const unsigned short* A0 = A + (size_t)(bm + r0) * 2048 + c0 * 8;
  const unsigned short* A1 = A + (size_t)(bm + r1) * 2048 + c1 * 8;
  const unsigned short* B0 = Wt + (size_t)(bn + r0) * 2048 + c0 * 8;
  const unsigned short* B1 = Wt + (size_t)(bn + r1) * 2048 + c1 * 8;

  const int m15 = lane & 15, q = lane >> 4;

  gld_lds16(A0, &As[0][wave * 64]);
  gld_lds16(A1, &As[0][256 + wave * 64]);
  gld_lds16(B0, &Bs[0][wave * 64]);
  gld_lds16(B1, &Bs[0][256 + wave * 64]);
  __syncthreads();

  int cur = 0;
  for (int kb = 0; kb < 3072; kb += 32) {
    const int kn = kb + 32;
    if (kn < 3072) {
      // segments: A_hi*W_hi | A_hi*W_lo | A_lo*W_hi
      int asrc = kn < 1024 ? kn : kn - 1024;
      int wsrc = kn < 2048 ? kn : kn - 2048;
      gld_lds16(A0 + asrc, &As[cur ^ 1][wave * 64]);
      gld_lds16(A1 + asrc, &As[cur ^ 1][256 + wave * 64]);
      gld_lds16(B0 + wsrc, &Bs[cur ^ 1][wave * 64]);
      gld_lds16(B1 + wsrc, &Bs[cur ^ 1][256 + wave * 64]);
    }

    s16x8 af[4], bf[4];
#pragma unroll
    for (int mt = 0; mt < 4; ++mt) {
      int r = wm * 64 + mt * 16 + m15;
      af[mt] = As[cur][r * 4 + (q ^ ((r >> 1) & 3))];
    }
#pragma unroll
    for (int nt = 0; nt < 4; ++nt) {
      int r = wn * 64 + nt * 16 + m15;
      bf[nt] = Bs[cur][r * 4 + (q ^ ((r >> 1) & 3))];
    }
#pragma unroll
    for (int mt = 0; mt < 4; ++mt)
#pragma unroll
      for (int nt = 0; nt < 4; ++nt)
        acc[mt][nt] = __builtin_amdgcn_mfma_f32_16x16x32_bf16(
            af[mt], bf[nt], acc[mt][nt], 0, 0, 0);

    if (kn < 3072) {
      __syncthreads();
      cur ^= 1;
    }
  }

#pragma unroll
  for (int nt = 0; nt < 4; ++nt) {
    int col = bn + wn * 64 + nt * 16 + m15;
    float bv = bias[col];
#pragma unroll
    for (int mt = 0; mt < 4; ++mt) {
      int rowb = bm + wm * 64 + mt * 16 + q * 4;
#pragma unroll
      for (int i = 0; i < 4; ++i) {
        float val = (acc[mt][nt][i] + bv) * scl;
        (Cbase + (size_t)z * QB_SLAB)[(size_t)(rowb + i) * 1024 + col] =
            f2bf(val);
      }
    }
  }
}

// ---------------------------------------------------------------------------
// Out-projection GEMM: 64x128 tile -> grid (8,64) = 512 blocks = 2 blocks/CU
// (v2 used 128x128 -> 256 blocks = 1/CU; barrier drain was unhidden).
// ---------------------------------------------------------------------------
__global__ __launch_bounds__(256, 2) void gemm_out(
    const unsigned short* __restrict__ A,   // XsAO [4096][2048]
    const unsigned short* __restrict__ Wt,  // Wo^T split [1024][2048]
    float* __restrict__ C, const float* __restrict__ bias) {
  __shared__ s16x8 As[2][256];
  __shared__ s16x8 Bs[2][512];
  const int t = threadIdx.x;
  const int lane = t & 63, wave = t >> 6;
  const int wm = wave & 1, wn = wave >> 1;
  const int bm = blockIdx.y * 64, bn = blockIdx.x * 128;

  f32x4 acc[2][4] = {};

  const int ra = t >> 2, ca = (t & 3) ^ ((ra >> 1) & 3);
  const int s0 = t, s1 = t + 256;
  const int r0 = s0 >> 2, c0 = (s0 & 3) ^ ((r0 >> 1) & 3);
  const int r1 = s1 >> 2, c1 = (s1 & 3) ^ ((r1 >> 1) & 3);
  const unsigned short* Ap = A + (size_t)(bm + ra) * 2048 + ca * 8;
  const unsigned short* B0 = Wt + (size_t)(bn + r0) * 2048 + c0 * 8;
  const unsigned short* B1 = Wt + (size_t)(bn + r1) * 2048 + c1 * 8;

  const int m15 = lane & 15, q = lane >> 4;

  gld_lds16(Ap, &As[0][wave * 64]);
  gld_lds16(B0, &Bs[0][wave * 64]);
  gld_lds16(B1, &Bs[0][256 + wave * 64]);
  __syncthreads();

  int cur = 0;
  for (int kb = 0; kb < 3072; kb += 32) {
    const int kn = kb + 32;
    if (kn < 3072) {
      int asrc = kn < 1024 ? kn : kn - 1024;
      int wsrc = kn < 2048 ? kn : kn - 2048;
      gld_lds16(Ap + asrc, &As[cur ^ 1][wave * 64]);
      gld_lds16(B0 + wsrc, &Bs[cur ^ 1][wave * 64]);
      gld_lds16(B1 + wsrc, &Bs[cur ^ 1][256 + wave * 64]);
    }

    s16x8 af[2], bf[4];
#pragma unroll
    for (int mt = 0; mt < 2; ++mt) {
      int r = wm * 32 + mt * 16 + m15;
      af[mt] = As[cur][r * 4 + (q ^ ((r >> 1) & 3))];
    }
#pragma unroll
    for (int nt = 0; nt < 4; ++nt) {
      int r = wn * 64 + nt * 16 + m15;
      bf[nt] = Bs[cur][r * 4 + (q ^ ((r >> 1) & 3))];
    }
#pragma unroll
    for (int mt = 0; mt < 2; ++mt)
#pragma unroll
      for (int nt = 0; nt < 4; ++nt)
        acc[mt][nt] = __builtin_amdgcn_mfma_f32_16x16x32_bf16(
            af[mt], bf[nt], acc[mt][nt], 0, 0, 0);

    if (kn < 3072) {
      __syncthreads();
      cur ^= 1;
    }
  }

#pragma unroll
  for (int nt = 0; nt < 4; ++nt) {
    int col = bn + wn * 64 + nt * 16 + m15;
    float bv = bias[col];
#pragma unroll
    for (int mt = 0; mt < 2; ++mt) {
      int rowb = bm + wm * 32 + mt * 16 + q * 4;
#pragma unroll
      for (int i = 0; i < 4; ++i) {
        __builtin_nontemporal_store(
            acc[mt][nt][i] + bv, &C[(size_t)(rowb + i) * 1024 + col]);
      }
    }
  }
}

// ---------------------------------------------------------------------------
// Vb [4096][1024] bf16 -> Vt [b][h][d][s] bf16 (per-head transposed).
// ---------------------------------------------------------------------------
__global__ __launch_bounds__(256) void transpose_v(
    const unsigned short* __restrict__ Vb, unsigned short* __restrict__ Vt) {
  __shared__ unsigned short T[64][88];
  const int b = blockIdx.z, h = blockIdx.y, s0 = blockIdx.x * 64;
  const int t = threadIdx.x;
  {
    int row = t >> 2, part = t & 3;
    const unsigned short* src =
        Vb + (size_t)(b * Ss + s0 + row) * 1024 + h * 64 + part * 16;
    s16x8 v0 = *(const s16x8*)src;
    s16x8 v1 = *(const s16x8*)(src + 8);
    *(s16x8*)&T[row][part * 16] = v0;
    *(s16x8*)&T[row][part * 16 + 8] = v1;
  }
  __syncthreads();
  {
    int d = t & 63, sw = t >> 6;
    unsigned short tmp[16];
#pragma unroll
    for (int i = 0; i < 16; ++i) tmp[i] = T[sw * 16 + i][d];
    unsigned short* dst =
        Vt + ((size_t)((b * Hh + h) * 64 + d)) * 2048 + s0 + sw * 16;
    *(s16x8*)dst = *(const s16x8*)&tmp[0];
    *(s16x8*)(dst + 8) = *(const s16x8*)&tmp[8];
  }
}

// ---------------------------------------------------------------------------
// Fused attention v4: per block = one (b,h) x 16-query tile, 4 waves.
// S1: scores via MFMA (Q pre-scaled 1/8) -> LDS P fp32.   [setprio on MFMA]
// S2: per-row softmax; write full 2048-wide attn rows (nontemporal).
// S3: PV via MFMA; epilogue writes AO as hi/lo bf16 (Xs layout).
// Barriers are lgkmcnt-only (raw s_barrier): the 128 KB/block attn store
// stream drains under S3 compute instead of stalling at vmcnt(0).
// ---------------------------------------------------------------------------
constexpr int SW3 = 556;  // f32 stride: 556%32=12 -> <=2-way banks; 16B-aligned
__global__ __launch_bounds__(256) void attn_v4(
    const unsigned short* __restrict__ Qb, const unsigned short* __restrict__ Kb,
    const unsigned short* __restrict__ Vt, float* __restrict__ attn,
    unsigned short* __restrict__ XsAO) {
  __shared__ float P[16 * SW3];  // 35.6 KB
  const int t = threadIdx.x;
  const int lane = t & 63, wave = t >> 6;
  const int m15 = lane & 15, quad = lane >> 4;
  const int bid = blockIdx.x;
  const int qt = bid & 127, h = (bid >> 7) & 15, b = bid >> 11;
  const int q0 = qt * 16;
  int jlo = q0 - WINw; if (jlo < 0) jlo = 0;
  int jhi = q0 + 15 + WINw; if (jhi > Ss - 1) jhi = Ss - 1;
  const int ncols = jhi - jlo + 1;  // always a multiple of 16
  const int ntiles = ncols >> 4;

  // ---- stage 1: scores via MFMA -> P ----
  {
    const unsigned short* qrow =
        Qb + (size_t)(b * Ss + q0 + m15) * 1024 + h * 64 + quad * 8;
    s16x8 aq0 = *(const s16x8*)qrow;
    s16x8 aq1 = *(const s16x8*)(qrow + 32);
    for (int nt = wave; nt < ntiles; nt += 4) {
      const unsigned short* krow =
          Kb + (size_t)(b * Ss + jlo + nt * 16 + m15) * 1024 + h * 64 + quad * 8;
      s16x8 b0 = *(const s16x8*)krow;
      s16x8 b1 = *(const s16x8*)(krow + 32);
      f32x4 c = {0.f, 0.f, 0.f, 0.f};
      __builtin_amdgcn_s_setprio(1);
      c = __builtin_amdgcn_mfma_f32_16x16x32_bf16(aq0, b0, c, 0, 0, 0);
      c = __builtin_amdgcn_mfma_f32_16x16x32_bf16(aq1, b1, c, 0, 0, 0);
      __builtin_amdgcn_s_setprio(0);
      float* pp = &P[(quad * 4) * SW3 + nt * 16 + m15];
#pragma unroll
      for (int i = 0; i < 4; ++i) pp[i * SW3] = c[i];
    }
  }
  lgkm_barrier();

  // ---- stage 2: softmax + attn row write + probs -> LDS ----
  {
#pragma unroll
    for (int ri = 0; ri < 4; ++ri) {
      const int r = wave * 4 + ri;
      const int qq = q0 + r;
      int lo = qq - WINw; if (lo < 0) lo = 0;
      int hi = qq + WINw; if (hi > Ss - 1) hi = Ss - 1;
      const int clo = lo - jlo, chi = hi - jlo;
      float sv[9];
      bool ib[9];
      float m = -1e30f;
#pragma unroll
      for (int k2 = 0; k2 < 9; ++k2) {
        int c = k2 * 64 + lane;
        bool inb = (c >= clo) && (c <= chi);
        ib[k2] = inb;
        float vv = inb ? P[r * SW3 + c] : -1e30f;
        sv[k2] = vv;
        m = fmaxf(m, vv);
      }
#pragma unroll
      for (int off = 32; off; off >>= 1) m = fmaxf(m, __shfl_xor(m, off, 64));
      float e[9], l = 0.f;
#pragma unroll
      for (int k2 = 0; k2 < 9; ++k2) { e[k2] = __expf(sv[k2] - m); l += e[k2]; }
#pragma unroll
      for (int off = 32; off; off >>= 1) l += __shfl_xor(l, off, 64);
      const float inv = 1.f / l;
#pragma unroll
      for (int k2 = 0; k2 < 9; ++k2) {
        int c = k2 * 64 + lane;
        if (c < 544) P[r * SW3 + c] = ib[k2] ? e[k2] * inv : 0.f;
      }
      float* arow = attn + ((size_t)((b * Hh + h) * Ss + qq)) * Ss;
#pragma unroll
      for (int i = 0; i < 8; ++i) {
        int col = i * 256 + lane * 4;
        int c = col - jlo;
        f32x4 v = {0.f, 0.f, 0.f, 0.f};
        if (c >= 0 && c <= 540) v = *(const f32x4*)&P[r * SW3 + c];
        __builtin_nontemporal_store(v, (f32x4*)&arow[col]);
      }
    }
  }
  lgkm_barrier();

  // ---- stage 3: PV via MFMA; wave = d-tile ----
  {
    const int ntk = (ncols + 31) >> 5;
    const unsigned short* vtrow =
        Vt + ((size_t)((b * Hh + h) * 64 + wave * 16 + m15)) * 2048 + jlo +
        quad * 8;
    f32x4 o = {0.f, 0.f, 0.f, 0.f};
    for (int ks = 0; ks < ntk; ++ks) {
      const float* pa = &P[m15 * SW3 + ks * 32 + quad * 8];
      f32x4 p0 = *(const f32x4*)pa;
      f32x4 p1 = *(const f32x4*)(pa + 4);
      s16x8 af;
#pragma unroll
      for (int i = 0; i < 4; ++i) af[i] = (short)f2bf(p0[i]);
#pragma unroll
      for (int i = 0; i < 4; ++i) af[4 + i] = (short)f2bf(p1[i]);
      s16x8 bf = *(const s16x8*)(vtrow + ks * 32);
      __builtin_amdgcn_s_setprio(1);
      o = __builtin_amdgcn_mfma_f32_16x16x32_bf16(af, bf, o, 0, 0, 0);
      __builtin_amdgcn_s_setprio(0);
    }
    const int dcol = h * 64 + wave * 16 + m15;
#pragma unroll
    for (int i = 0; i < 4; ++i) {
      int row = q0 + quad * 4 + i;
      unsigned short hi = f2bf(o[i]);
      unsigned short lo = f2bf(o[i] - bf2f(hi));
      unsigned short* dst = XsAO + (size_t)(b * Ss + row) * 2048 + dcol;
      dst[0] = hi;
      dst[1024] = lo;
    }
  }
}

// ---------------------------------------------------------------------------
extern "C" void kernel_launch(void* const* d_in, const int* in_sizes, int n_in,
                              void* d_out, int out_size, void* d_ws,
                              size_t ws_size, hipStream_t stream) {
  const float* q  = (const float*)d_in[0];
  const float* k  = (const float*)d_in[1];
  const float* v  = (const float*)d_in[2];
  const float* Wq = (const float*)d_in[3];
  const float* bq = (const float*)d_in[4];
  const float* Wk = (const float*)d_in[5];
  const float* bk = (const float*)d_in[6];
  const float* Wv = (const float*)d_in[7];
  const float* bv = (const float*)d_in[8];
  const float* Wo = (const float*)d_in[9];
  const float* bo = (const float*)d_in[10];

  float* out = (float*)d_out;
  float* attn = out + (size_t)Bb * Ss * Dd;

  unsigned short* Xs   = (unsigned short*)d_ws;   // 48 MB
  unsigned short* XsAO = Xs + 3 * XS_SLAB;        // 16 MB
  unsigned short* Wt   = XsAO + XS_SLAB;          // 16 MB
  unsigned short* Qb   = Wt + 4 * WT_SLAB;        // 8 MB
  unsigned short* Kb   = Qb + QB_SLAB;            // 8 MB
  unsigned short* Vb   = Kb + QB_SLAB;            // 8 MB
  unsigned short* Vt   = Vb + QB_SLAB;            // 8 MB (+slack after)

  hipLaunchKernelGGL(convert_xw, dim3(12288 + 1024), dim3(256), 0, stream,
                     q, k, v, Xs, Wq, Wk, Wv, Wo, Wt);
  hipLaunchKernelGGL(gemm_qkv, dim3(8, 32, 3), dim3(256), 0, stream,
                     Xs, Wt, Qb, bq, bk, bv);
  hipLaunchKernelGGL(transpose_v, dim3(32, 16, 2), dim3(256), 0, stream,
                     Vb, Vt);
  hipLaunchKernelGGL(attn_v4, dim3(Bb * Hh * (Ss / 16)), dim3(256), 0, stream,
                     Qb, Kb, Vt, attn, XsAO);
  hipLaunchKernelGGL(gemm_out, dim3(8, 64, 1), dim3(256), 0, stream,
                     XsAO, Wt + 3 * WT_SLAB, out, bo);
}

// Round 4
// 779.319 us; speedup vs baseline: 1.0532x; 1.0061x over previous
//
#include <hip/hip_runtime.h>

// B=2, S=2048, D=1024, H=16, d_k=64, WINDOW=256
// d_out = out [B,S,D] fp32  ++  attn [B,H,S,S] fp32
// ws (112 MB): Xs bf16 3x[4096x2048] | XsAO bf16 [4096x2048] | Wt bf16 4x[1024x2048]
//              | Qb,Kb,Vb bf16 [4096x1024] | Vt bf16 [B,H,64,2048]
//
// v6: the 512MB attn matrix's zero region is written ENTIRELY by gemm_qkv
// (which runs BEFORE attn on the stream) on idle HBM write BW. attn then
// overwrites only the band (<=528 cols/row). v5's bug: gemm_out (which runs
// AFTER attn) dripped zeros over the band's last 112MB.

constexpr int Bb = 2, Ss = 2048, Dd = 1024, Hh = 16, WINw = 256;
constexpr size_t XS_SLAB = (size_t)4096 * 2048;  // bf16 elems
constexpr size_t WT_SLAB = (size_t)1024 * 2048;  // bf16 elems
constexpr size_t QB_SLAB = (size_t)4096 * 1024;  // bf16 elems
constexpr size_t ATTN_BYTES = (size_t)Bb * Hh * Ss * Ss * 4;  // 512 MiB

typedef short s16x8 __attribute__((ext_vector_type(8)));
typedef float f32x4 __attribute__((ext_vector_type(4)));

typedef __attribute__((address_space(3))) unsigned int lds_uint;
typedef const __attribute__((address_space(1))) unsigned int gbl_uint;

// async global->LDS, 16B per lane; LDS dest = wave-uniform base + lane*16
__device__ __forceinline__ void gld_lds16(const void* g, void* l) {
  __builtin_amdgcn_global_load_lds((gbl_uint*)g, (lds_uint*)l, 16, 0, 0);
}

// LDS-only drain + barrier (lets global stores keep draining across it)
__device__ __forceinline__ void lgkm_barrier() {
  asm volatile("s_waitcnt lgkmcnt(0)" ::: "memory");
  __builtin_amdgcn_s_barrier();
}

__device__ inline unsigned short f2bf(float x) {
  unsigned u = __float_as_uint(x);
  u += 0x7fff + ((u >> 16) & 1);  // RNE
  return (unsigned short)(u >> 16);
}
__device__ inline float bf2f(unsigned short h) {
  return __uint_as_float(((unsigned)h) << 16);
}

// ---------------------------------------------------------------------------
// Merged conversions (single dispatch).
// id < 12288 : convert_x — fp32 [4096x1024] -> bf16 split [4096x2048]=[hi|lo]
// id >= 12288: convert_w — W [1024x1024] fp32 -> Wt bf16 [n][2048]=[Whi^T|Wlo^T]
// ---------------------------------------------------------------------------
__global__ __launch_bounds__(256) void convert_xw(
    const float* __restrict__ x0, const float* __restrict__ x1,
    const float* __restrict__ x2, unsigned short* __restrict__ Xs,
    const float* __restrict__ w0, const float* __restrict__ w1,
    const float* __restrict__ w2, const float* __restrict__ w3,
    unsigned short* __restrict__ Wt) {
  __shared__ float T[64][65];
  const int id = blockIdx.x;
  const int t = threadIdx.x;
  if (id < 12288) {
    int z = id >> 12;
    int bx = id & 4095;
    const float* src = z == 0 ? x0 : (z == 1 ? x1 : x2);
    unsigned short* dst = Xs + (size_t)z * XS_SLAB;
    size_t idx = ((size_t)bx * 256 + t) * 4;
    int r = (int)(idx >> 10);
    int c = (int)(idx & 1023);
    f32x4 v = *(const f32x4*)&src[idx];
    unsigned short hi[4], lo[4];
#pragma unroll
    for (int i = 0; i < 4; ++i) {
      float vi = v[i];
      hi[i] = f2bf(vi);
      lo[i] = f2bf(vi - bf2f(hi[i]));
    }
    ushort4 h4 = {hi[0], hi[1], hi[2], hi[3]};
    ushort4 l4 = {lo[0], lo[1], lo[2], lo[3]};
    *(ushort4*)&dst[(size_t)r * 2048 + c] = h4;
    *(ushort4*)&dst[(size_t)r * 2048 + 1024 + c] = l4;
  } else {
    int wid = id - 12288;
    int z = wid >> 8;
    int by = (wid >> 4) & 15;
    int bx = wid & 15;
    const float* W = z == 0 ? w0 : (z == 1 ? w1 : (z == 2 ? w2 : w3));
    unsigned short* dst = Wt + (size_t)z * WT_SLAB;
    int k0 = by * 64, n0 = bx * 64;
#pragma unroll
    for (int i = 0; i < 4; ++i) {
      int row = (t >> 4) + i * 16;
      int c4 = (t & 15) * 4;
      f32x4 v = *(const f32x4*)&W[(size_t)(k0 + row) * 1024 + n0 + c4];
      T[row][c4 + 0] = v[0]; T[row][c4 + 1] = v[1];
      T[row][c4 + 2] = v[2]; T[row][c4 + 3] = v[3];
    }
    __syncthreads();
    int n = t >> 2;
    int kc = (t & 3) * 16;
    unsigned short hi[16], lo[16];
#pragma unroll
    for (int j = 0; j < 16; ++j) {
      float x = T[kc + j][n];
      hi[j] = f2bf(x);
      lo[j] = f2bf(x - bf2f(hi[j]));
    }
    size_t base = (size_t)(n0 + n) * 2048 + k0 + kc;
#pragma unroll
    for (int j4 = 0; j4 < 4; ++j4) {
      ushort4 h4 = {hi[j4 * 4], hi[j4 * 4 + 1], hi[j4 * 4 + 2], hi[j4 * 4 + 3]};
      ushort4 l4 = {lo[j4 * 4], lo[j4 * 4 + 1], lo[j4 * 4 + 2], lo[j4 * 4 + 3]};
      *(ushort4*)&dst[base + j4 * 4] = h4;
      *(ushort4*)&dst[base + 1024 + j4 * 4] = l4;
    }
  }
}

// ---------------------------------------------------------------------------
// QKV GEMM: C[4096x1024] = A[4096x3072] @ W[3072x1024] + bias (bf16x3 split).
// 128x128 tile, global_load_lds double-buffer. XCD-swizzled block map.
// Drip-writes the FULL attn zero buffer [0, ATTN_BYTES) on idle write BW:
// 3072 waves x 96 K-steps x 2KB = 604MB coverage >= 512MB (guarded).
// ---------------------------------------------------------------------------
__global__ __launch_bounds__(256, 3) void gemm_qkv(
    const unsigned short* __restrict__ Abase,
    const unsigned short* __restrict__ Wtbase,
    unsigned short* __restrict__ Cbase, const float* __restrict__ bb0,
    const float* __restrict__ bb1, const float* __restrict__ bb2,
    float* __restrict__ attnz) {
  __shared__ s16x8 As[2][512];
  __shared__ s16x8 Bs[2][512];
  int z = blockIdx.z;
  const unsigned short* A = Abase + (size_t)z * XS_SLAB;
  const unsigned short* Wt = Wtbase + (size_t)z * WT_SLAB;
  const float* bias = z == 0 ? bb0 : (z == 1 ? bb1 : bb2);
  const float scl = (z == 0) ? 0.125f : 1.0f;

  const int t = threadIdx.x;
  const int lane = t & 63, wave = t >> 6;
  const int wm = wave & 1, wn = wave >> 1;

  // XCD swizzle: flat = bn-fast id; XCD c gets bm in [4c, 4c+4) x all bn.
  const int flat = blockIdx.x + (blockIdx.y << 3);          // 0..255
  const int swz = (flat & 7) * 32 + (flat >> 3);
  const int bm = (swz >> 3) * 128, bn = (swz & 7) * 128;

  // attn-zero drip state: contiguous 192KB chunk per wave
  const int flat3 = flat + (z << 8);                        // 0..767
  const size_t zbase = (size_t)(flat3 * 4 + wave) * 196608;
  char* const az = (char*)attnz;
  const f32x4 zv = {0.f, 0.f, 0.f, 0.f};

  f32x4 acc[4][4] = {};

  const int s0 = t, s1 = t + 256;
  const int r0 = s0 >> 2, c0 = (s0 & 3) ^ ((r0 >> 1) & 3);
  const int r1 = s1 >> 2, c1 = (s1 & 3) ^ ((r1 >> 1) & 3);
  const unsigned short* A0 = A + (size_t)(bm + r0) * 2048 + c0 * 8;
  const unsigned short* A1 = A + (size_t)(bm + r1) * 2048 + c1 * 8;
  const unsigned short* B0 = Wt + (size_t)(bn + r0) * 2048 + c0 * 8;
  const unsigned short* B1 = Wt + (size_t)(bn + r1) * 2048 + c1 * 8;

  const int m15 = lane & 15, q = lane >> 4;

  gld_lds16(A0, &As[0][wave * 64]);
  gld_lds16(A1, &As[0][256 + wave * 64]);
  gld_lds16(B0, &Bs[0][wave * 64]);
  gld_lds16(B1, &Bs[0][256 + wave * 64]);
  __syncthreads();

  int cur = 0;
  for (int kb = 0; kb < 3072; kb += 32) {
    const int kn = kb + 32;
    if (kn < 3072) {
      // segments: A_hi*W_hi | A_hi*W_lo | A_lo*W_hi
      int asrc = kn < 1024 ? kn : kn - 1024;
      int wsrc = kn < 2048 ? kn : kn - 2048;
      gld_lds16(A0 + asrc, &As[cur ^ 1][wave * 64]);
      gld_lds16(A1 + asrc, &As[cur ^ 1][256 + wave * 64]);
      gld_lds16(B0 + wsrc, &Bs[cur ^ 1][wave * 64]);
      gld_lds16(B1 + wsrc, &Bs[cur ^ 1][256 + wave * 64]);
    }

    // attn-zero drip: two 1KB NT store rows per wave per K-step
    {
      size_t off = zbase + (size_t)(kb >> 5) * 2048 + (size_t)(lane << 4);
      if (off < ATTN_BYTES) __builtin_nontemporal_store(zv, (f32x4*)(az + off));
      off += 1024;
      if (off < ATTN_BYTES) __builtin_nontemporal_store(zv, (f32x4*)(az + off));
    }

    s16x8 af[4], bf[4];
#pragma unroll
    for (int mt = 0; mt < 4; ++mt) {
      int r = wm * 64 + mt * 16 + m15;
      af[mt] = As[cur][r * 4 + (q ^ ((r >> 1) & 3))];
    }
#pragma unroll
    for (int nt = 0; nt < 4; ++nt) {
      int r = wn * 64 + nt * 16 + m15;
      bf[nt] = Bs[cur][r * 4 + (q ^ ((r >> 1) & 3))];
    }
#pragma unroll
    for (int mt = 0; mt < 4; ++mt)
#pragma unroll
      for (int nt = 0; nt < 4; ++nt)
        acc[mt][nt] = __builtin_amdgcn_mfma_f32_16x16x32_bf16(
            af[mt], bf[nt], acc[mt][nt], 0, 0, 0);

    if (kn < 3072) {
      __syncthreads();
      cur ^= 1;
    }
  }

#pragma unroll
  for (int nt = 0; nt < 4; ++nt) {
    int col = bn + wn * 64 + nt * 16 + m15;
    float bv = bias[col];
#pragma unroll
    for (int mt = 0; mt < 4; ++mt) {
      int rowb = bm + wm * 64 + mt * 16 + q * 4;
#pragma unroll
      for (int i = 0; i < 4; ++i) {
        float val = (acc[mt][nt][i] + bv) * scl;
        (Cbase + (size_t)z * QB_SLAB)[(size_t)(rowb + i) * 1024 + col] =
            f2bf(val);
      }
    }
  }
}

// ---------------------------------------------------------------------------
// Out-projection GEMM: 64x128 tile, 512 blocks = 2/CU. XCD-swizzled.
// (No zero drip: this kernel runs AFTER attn — v5's correctness bug.)
// ---------------------------------------------------------------------------
__global__ __launch_bounds__(256, 2) void gemm_out(
    const unsigned short* __restrict__ A,   // XsAO [4096][2048]
    const unsigned short* __restrict__ Wt,  // Wo^T split [1024][2048]
    float* __restrict__ C, const float* __restrict__ bias) {
  __shared__ s16x8 As[2][256];
  __shared__ s16x8 Bs[2][512];
  const int t = threadIdx.x;
  const int lane = t & 63, wave = t >> 6;
  const int wm = wave & 1, wn = wave >> 1;

  const int flat = blockIdx.x + (blockIdx.y << 3);          // 0..511
  const int swz = (flat & 7) * 64 + (flat >> 3);
  const int bm = (swz >> 3) * 64, bn = (swz & 7) * 128;

  f32x4 acc[2][4] = {};

  const int ra = t >> 2, ca = (t & 3) ^ ((ra >> 1) & 3);
  const int s0 = t, s1 = t + 256;
  const int r0 = s0 >> 2, c0 = (s0 & 3) ^ ((r0 >> 1) & 3);
  const int r1 = s1 >> 2, c1 = (s1 & 3) ^ ((r1 >> 1) & 3);
  const unsigned short* Ap = A + (size_t)(bm + ra) * 2048 + ca * 8;
  const unsigned short* B0 = Wt + (size_t)(bn + r0) * 2048 + c0 * 8;
  const unsigned short* B1 = Wt + (size_t)(bn + r1) * 2048 + c1 * 8;

  const int m15 = lane & 15, q = lane >> 4;

  gld_lds16(Ap, &As[0][wave * 64]);
  gld_lds16(B0, &Bs[0][wave * 64]);
  gld_lds16(B1, &Bs[0][256 + wave * 64]);
  __syncthreads();

  int cur = 0;
  for (int kb = 0; kb < 3072; kb += 32) {
    const int kn = kb + 32;
    if (kn < 3072) {
      int asrc = kn < 1024 ? kn : kn - 1024;
      int wsrc = kn < 2048 ? kn : kn - 2048;
      gld_lds16(Ap + asrc, &As[cur ^ 1][wave * 64]);
      gld_lds16(B0 + wsrc, &Bs[cur ^ 1][wave * 64]);
      gld_lds16(B1 + wsrc, &Bs[cur ^ 1][256 + wave * 64]);
    }

    s16x8 af[2], bf[4];
#pragma unroll
    for (int mt = 0; mt < 2; ++mt) {
      int r = wm * 32 + mt * 16 + m15;
      af[mt] = As[cur][r * 4 + (q ^ ((r >> 1) & 3))];
    }
#pragma unroll
    for (int nt = 0; nt < 4; ++nt) {
      int r = wn * 64 + nt * 16 + m15;
      bf[nt] = Bs[cur][r * 4 + (q ^ ((r >> 1) & 3))];
    }
#pragma unroll
    for (int mt = 0; mt < 2; ++mt)
#pragma unroll
      for (int nt = 0; nt < 4; ++nt)
        acc[mt][nt] = __builtin_amdgcn_mfma_f32_16x16x32_bf16(
            af[mt], bf[nt], acc[mt][nt], 0, 0, 0);

    if (kn < 3072) {
      __syncthreads();
      cur ^= 1;
    }
  }

#pragma unroll
  for (int nt = 0; nt < 4; ++nt) {
    int col = bn + wn * 64 + nt * 16 + m15;
    float bv = bias[col];
#pragma unroll
    for (int mt = 0; mt < 2; ++mt) {
      int rowb = bm + wm * 32 + mt * 16 + q * 4;
#pragma unroll
      for (int i = 0; i < 4; ++i) {
        __builtin_nontemporal_store(
            acc[mt][nt][i] + bv, &C[(size_t)(rowb + i) * 1024 + col]);
      }
    }
  }
}

// ---------------------------------------------------------------------------
// Vb [4096][1024] bf16 -> Vt [b][h][d][s] bf16 (per-head transposed).
// ---------------------------------------------------------------------------
__global__ __launch_bounds__(256) void transpose_v(
    const unsigned short* __restrict__ Vb, unsigned short* __restrict__ Vt) {
  __shared__ unsigned short T[64][88];
  const int b = blockIdx.z, h = blockIdx.y, s0 = blockIdx.x * 64;
  const int t = threadIdx.x;
  {
    int row = t >> 2, part = t & 3;
    const unsigned short* src =
        Vb + (size_t)(b * Ss + s0 + row) * 1024 + h * 64 + part * 16;
    s16x8 v0 = *(const s16x8*)src;
    s16x8 v1 = *(const s16x8*)(src + 8);
    *(s16x8*)&T[row][part * 16] = v0;
    *(s16x8*)&T[row][part * 16 + 8] = v1;
  }
  __syncthreads();
  {
    int d = t & 63, sw = t >> 6;
    unsigned short tmp[16];
#pragma unroll
    for (int i = 0; i < 16; ++i) tmp[i] = T[sw * 16 + i][d];
    unsigned short* dst =
        Vt + ((size_t)((b * Hh + h) * 64 + d)) * 2048 + s0 + sw * 16;
    *(s16x8*)dst = *(const s16x8*)&tmp[0];
    *(s16x8*)(dst + 8) = *(const s16x8*)&tmp[8];
  }
}

// ---------------------------------------------------------------------------
// Fused attention v5: per block = one (b,h) x 16-query tile, 4 waves.
// S1: scores via MFMA -> LDS P.  S2: softmax; write BAND ONLY (cols
// [jlo..jhi], zeros pre-written by gemm_qkv).  S3: PV via MFMA -> XsAO.
// ---------------------------------------------------------------------------
constexpr int SW3 = 556;  // f32 stride: 556%32=12 -> <=2-way banks; 16B-aligned
__global__ __launch_bounds__(256) void attn_v5(
    const unsigned short* __restrict__ Qb, const unsigned short* __restrict__ Kb,
    const unsigned short* __restrict__ Vt, float* __restrict__ attn,
    unsigned short* __restrict__ XsAO) {
  __shared__ float P[16 * SW3];  // 35.6 KB
  const int t = threadIdx.x;
  const int lane = t & 63, wave = t >> 6;
  const int m15 = lane & 15, quad = lane >> 4;
  const int bid = blockIdx.x;
  const int qt = bid & 127, h = (bid >> 7) & 15, b = bid >> 11;
  const int q0 = qt * 16;
  int jlo = q0 - WINw; if (jlo < 0) jlo = 0;
  int jhi = q0 + 15 + WINw; if (jhi > Ss - 1) jhi = Ss - 1;
  const int ncols = jhi - jlo + 1;  // multiple of 16, <=528
  const int ntiles = ncols >> 4;

  // ---- stage 1: scores via MFMA -> P ----
  {
    const unsigned short* qrow =
        Qb + (size_t)(b * Ss + q0 + m15) * 1024 + h * 64 + quad * 8;
    s16x8 aq0 = *(const s16x8*)qrow;
    s16x8 aq1 = *(const s16x8*)(qrow + 32);
    for (int nt = wave; nt < ntiles; nt += 4) {
      const unsigned short* krow =
          Kb + (size_t)(b * Ss + jlo + nt * 16 + m15) * 1024 + h * 64 + quad * 8;
      s16x8 b0 = *(const s16x8*)krow;
      s16x8 b1 = *(const s16x8*)(krow + 32);
      f32x4 c = {0.f, 0.f, 0.f, 0.f};
      __builtin_amdgcn_s_setprio(1);
      c = __builtin_amdgcn_mfma_f32_16x16x32_bf16(aq0, b0, c, 0, 0, 0);
      c = __builtin_amdgcn_mfma_f32_16x16x32_bf16(aq1, b1, c, 0, 0, 0);
      __builtin_amdgcn_s_setprio(0);
      float* pp = &P[(quad * 4) * SW3 + nt * 16 + m15];
#pragma unroll
      for (int i = 0; i < 4; ++i) pp[i * SW3] = c[i];
    }
  }
  lgkm_barrier();

  // ---- stage 2: softmax + band-only attn write + probs -> LDS ----
  {
#pragma unroll
    for (int ri = 0; ri < 4; ++ri) {
      const int r = wave * 4 + ri;
      const int qq = q0 + r;
      int lo = qq - WINw; if (lo < 0) lo = 0;
      int hi = qq + WINw; if (hi > Ss - 1) hi = Ss - 1;
      const int clo = lo - jlo, chi = hi - jlo;
      float sv[9];
      bool ib[9];
      float m = -1e30f;
#pragma unroll
      for (int k2 = 0; k2 < 9; ++k2) {
        int c = k2 * 64 + lane;
        bool inb = (c >= clo) && (c <= chi);
        ib[k2] = inb;
        float vv = inb ? P[r * SW3 + c] : -1e30f;
        sv[k2] = vv;
        m = fmaxf(m, vv);
      }
#pragma unroll
      for (int off = 32; off; off >>= 1) m = fmaxf(m, __shfl_xor(m, off, 64));
      float e[9], l = 0.f;
#pragma unroll
      for (int k2 = 0; k2 < 9; ++k2) { e[k2] = __expf(sv[k2] - m); l += e[k2]; }
#pragma unroll
      for (int off = 32; off; off >>= 1) l += __shfl_xor(l, off, 64);
      const float inv = 1.f / l;
#pragma unroll
      for (int k2 = 0; k2 < 9; ++k2) {
        int c = k2 * 64 + lane;
        if (c < 544) P[r * SW3 + c] = ib[k2] ? e[k2] * inv : 0.f;
      }
      // band-only write: cols [jlo, jlo+ncols)
      float* arow = attn + ((size_t)((b * Hh + h) * Ss + qq)) * Ss + jlo;
#pragma unroll
      for (int i = 0; i < 3; ++i) {
        int c = i * 256 + lane * 4;
        if (c < ncols) {
          f32x4 v = *(const f32x4*)&P[r * SW3 + c];
          __builtin_nontemporal_store(v, (f32x4*)&arow[c]);
        }
      }
    }
  }
  lgkm_barrier();

  // ---- stage 3: PV via MFMA; wave = d-tile ----
  {
    const int ntk = (ncols + 31) >> 5;
    const unsigned short* vtrow =
        Vt + ((size_t)((b * Hh + h) * 64 + wave * 16 + m15)) * 2048 + jlo +
        quad * 8;
    f32x4 o = {0.f, 0.f, 0.f, 0.f};
    for (int ks = 0; ks < ntk; ++ks) {
      const float* pa = &P[m15 * SW3 + ks * 32 + quad * 8];
      f32x4 p0 = *(const f32x4*)pa;
      f32x4 p1 = *(const f32x4*)(pa + 4);
      s16x8 af;
#pragma unroll
      for (int i = 0; i < 4; ++i) af[i] = (short)f2bf(p0[i]);
#pragma unroll
      for (int i = 0; i < 4; ++i) af[4 + i] = (short)f2bf(p1[i]);
      s16x8 bf = *(const s16x8*)(vtrow + ks * 32);
      __builtin_amdgcn_s_setprio(1);
      o = __builtin_amdgcn_mfma_f32_16x16x32_bf16(af, bf, o, 0, 0, 0);
      __builtin_amdgcn_s_setprio(0);
    }
    const int dcol = h * 64 + wave * 16 + m15;
#pragma unroll
    for (int i = 0; i < 4; ++i) {
      int row = q0 + quad * 4 + i;
      unsigned short hi = f2bf(o[i]);
      unsigned short lo = f2bf(o[i] - bf2f(hi));
      unsigned short* dst = XsAO + (size_t)(b * Ss + row) * 2048 + dcol;
      dst[0] = hi;
      dst[1024] = lo;
    }
  }
}

// ---------------------------------------------------------------------------
extern "C" void kernel_launch(void* const* d_in, const int* in_sizes, int n_in,
                              void* d_out, int out_size, void* d_ws,
                              size_t ws_size, hipStream_t stream) {
  const float* q  = (const float*)d_in[0];
  const float* k  = (const float*)d_in[1];
  const float* v  = (const float*)d_in[2];
  const float* Wq = (const float*)d_in[3];
  const float* bq = (const float*)d_in[4];
  const float* Wk = (const float*)d_in[5];
  const float* bk = (const float*)d_in[6];
  const float* Wv = (const float*)d_in[7];
  const float* bv = (const float*)d_in[8];
  const float* Wo = (const float*)d_in[9];
  const float* bo = (const float*)d_in[10];

  float* out = (float*)d_out;
  float* attn = out + (size_t)Bb * Ss * Dd;

  unsigned short* Xs   = (unsigned short*)d_ws;   // 48 MB
  unsigned short* XsAO = Xs + 3 * XS_SLAB;        // 16 MB
  unsigned short* Wt   = XsAO + XS_SLAB;          // 16 MB
  unsigned short* Qb   = Wt + 4 * WT_SLAB;        // 8 MB
  unsigned short* Kb   = Qb + QB_SLAB;            // 8 MB
  unsigned short* Vb   = Kb + QB_SLAB;            // 8 MB
  unsigned short* Vt   = Vb + QB_SLAB;            // 8 MB (+slack after)

  hipLaunchKernelGGL(convert_xw, dim3(12288 + 1024), dim3(256), 0, stream,
                     q, k, v, Xs, Wq, Wk, Wv, Wo, Wt);
  hipLaunchKernelGGL(gemm_qkv, dim3(8, 32, 3), dim3(256), 0, stream,
                     Xs, Wt, Qb, bq, bk, bv, attn);
  hipLaunchKernelGGL(transpose_v, dim3(32, 16, 2), dim3(256), 0, stream,
                     Vb, Vt);
  hipLaunchKernelGGL(attn_v5, dim3(Bb * Hh * (Ss / 16)), dim3(256), 0, stream,
                     Qb, Kb, Vt, attn, XsAO);
  hipLaunchKernelGGL(gemm_out, dim3(8, 64, 1), dim3(256), 0, stream,
                     XsAO, Wt + 3 * WT_SLAB, out, bo);
}